// Round 1
// baseline (2630.083 us; speedup 1.0000x reference)
//
#include <hip/hip_runtime.h>
#include <math.h>

#define D_MODEL 1024
#define D_INNER 2048
#define DT_RANK 64
#define NSTATE  16
#define BATCH   4
#define SEQ     1024
#define NTOK    (BATCH * SEQ)   // 4096 tokens

// ---------------------------------------------------------------------------
// Generic fp32 GEMM:  C[M,N] = A[M,K] * W[N,K]^T
// 128x128 tile, BK=16, 256 threads, 8x8 micro-tile per thread.
// M assumed multiple of 128, K multiple of 16; N guarded (for N=96 case).
// ---------------------------------------------------------------------------
__global__ __launch_bounds__(256) void gemm_nt(
    const float* __restrict__ A, const float* __restrict__ W, float* __restrict__ C,
    int M, int N, int K, int lda, int ldw, int ldc)
{
    __shared__ float As[128][17];
    __shared__ float Ws[128][17];

    const int tid = threadIdx.x;
    const int m0 = blockIdx.y * 128;
    const int n0 = blockIdx.x * 128;
    const int tx = tid & 15;        // 0..15 -> n
    const int ty = tid >> 4;        // 0..15 -> m
    const int lr = tid >> 1;        // 0..127 loader row
    const int lk = (tid & 1) * 8;   // 0 or 8 loader k offset

    float c[8][8];
    #pragma unroll
    for (int i = 0; i < 8; ++i)
        #pragma unroll
        for (int j = 0; j < 8; ++j) c[i][j] = 0.f;

    const float* Arow = A + (size_t)(m0 + lr) * lda + lk;
    const float* Wrow = W + (size_t)(n0 + lr) * ldw + lk;
    const bool wok = (n0 + lr) < N;

    for (int k0 = 0; k0 < K; k0 += 16) {
        float4 a0 = *(const float4*)(Arow + k0);
        float4 a1 = *(const float4*)(Arow + k0 + 4);
        float4 w0, w1;
        if (wok) {
            w0 = *(const float4*)(Wrow + k0);
            w1 = *(const float4*)(Wrow + k0 + 4);
        } else {
            w0 = make_float4(0.f, 0.f, 0.f, 0.f);
            w1 = make_float4(0.f, 0.f, 0.f, 0.f);
        }
        __syncthreads();   // previous compute done before overwriting LDS
        As[lr][lk + 0] = a0.x; As[lr][lk + 1] = a0.y; As[lr][lk + 2] = a0.z; As[lr][lk + 3] = a0.w;
        As[lr][lk + 4] = a1.x; As[lr][lk + 5] = a1.y; As[lr][lk + 6] = a1.z; As[lr][lk + 7] = a1.w;
        Ws[lr][lk + 0] = w0.x; Ws[lr][lk + 1] = w0.y; Ws[lr][lk + 2] = w0.z; Ws[lr][lk + 3] = w0.w;
        Ws[lr][lk + 4] = w1.x; Ws[lr][lk + 5] = w1.y; Ws[lr][lk + 6] = w1.z; Ws[lr][lk + 7] = w1.w;
        __syncthreads();

        #pragma unroll
        for (int kk = 0; kk < 16; ++kk) {
            float a[8], b[8];
            #pragma unroll
            for (int i = 0; i < 8; ++i) a[i] = As[ty * 8 + i][kk];
            #pragma unroll
            for (int j = 0; j < 8; ++j) b[j] = Ws[tx * 8 + j][kk];
            #pragma unroll
            for (int i = 0; i < 8; ++i)
                #pragma unroll
                for (int j = 0; j < 8; ++j)
                    c[i][j] = fmaf(a[i], b[j], c[i][j]);
        }
    }

    #pragma unroll
    for (int i = 0; i < 8; ++i) {
        const int m = m0 + ty * 8 + i;
        const int nb = n0 + tx * 8;
        float4 v0 = make_float4(c[i][0], c[i][1], c[i][2], c[i][3]);
        float4 v1 = make_float4(c[i][4], c[i][5], c[i][6], c[i][7]);
        if (nb + 4 <= N) *(float4*)(C + (size_t)m * ldc + nb) = v0;
        if (nb + 8 <= N) *(float4*)(C + (size_t)m * ldc + nb + 4) = v1;
    }
}

// ---------------------------------------------------------------------------
// Causal depthwise conv (width 4) + SiLU.  xr: [NTOK, 2*D_INNER], take cols
// [0, D_INNER).  Output xs: [NTOK, D_INNER].
// ---------------------------------------------------------------------------
__global__ __launch_bounds__(256) void conv_silu(
    const float* __restrict__ xr, const float* __restrict__ cw,
    const float* __restrict__ cb, float* __restrict__ xs)
{
    const int idx = blockIdx.x * 256 + threadIdx.x;   // over NTOK*D_INNER
    const int d = idx & (D_INNER - 1);
    const int t = idx >> 11;          // token = b*SEQ + l
    const int l = t & (SEQ - 1);

    float acc = cb[d];
    const float* col = xr + (size_t)t * (2 * D_INNER) + d;
    const float w0 = cw[d * 4 + 0], w1 = cw[d * 4 + 1], w2 = cw[d * 4 + 2], w3 = cw[d * 4 + 3];

    if (l >= 3) {
        acc = fmaf(w0, col[-3 * 2 * D_INNER], acc);
        acc = fmaf(w1, col[-2 * 2 * D_INNER], acc);
        acc = fmaf(w2, col[-1 * 2 * D_INNER], acc);
        acc = fmaf(w3, col[0], acc);
    } else {
        if (l >= 3) acc = fmaf(w0, col[-3 * 2 * D_INNER], acc);
        if (l >= 2) acc = fmaf(w1, col[-2 * 2 * D_INNER], acc);
        if (l >= 1) acc = fmaf(w2, col[-1 * 2 * D_INNER], acc);
        acc = fmaf(w3, col[0], acc);
    }
    xs[idx] = acc / (1.f + expf(-acc));   // SiLU
}

// ---------------------------------------------------------------------------
// delta = softplus(dt_lin + b_dt), in place.  [NTOK, D_INNER]
// ---------------------------------------------------------------------------
__global__ __launch_bounds__(256) void bias_softplus(
    float* __restrict__ v, const float* __restrict__ bias)
{
    const int idx = blockIdx.x * 256 + threadIdx.x;
    const int d = idx & (D_INNER - 1);
    float x = v[idx] + bias[d];
    v[idx] = (x > 20.f) ? x : log1pf(expf(x));
}

// ---------------------------------------------------------------------------
// Selective scan + skip (u*Dp) + SiLU(res) gate.
// One thread per (b,d) channel; 16 states in registers; loop over L.
// Writes yg in place of delta (read-before-write, same index).
// ---------------------------------------------------------------------------
__global__ __launch_bounds__(64) void scan_silu_gate(
    const float* __restrict__ u,       // xs   [NTOK, D_INNER]
    const float* delta,                // delta [NTOK, D_INNER] (aliases yg)
    const float* __restrict__ xdbl,    // [NTOK, 96]; B at col 64, C at col 80
    const float* __restrict__ A_log,   // [D_INNER, 16]
    const float* __restrict__ Dp,      // [D_INNER]
    const float* __restrict__ xr,      // res at col D_INNER+d, ld 2*D_INNER
    float* yg)                         // [NTOK, D_INNER] (aliases delta)
{
    const int t = blockIdx.x * 64 + threadIdx.x;   // 0..BATCH*D_INNER-1
    const int d = t & (D_INNER - 1);
    const int b = t >> 11;

    float A[NSTATE];
    #pragma unroll
    for (int n = 0; n < NSTATE; ++n) A[n] = -expf(A_log[d * NSTATE + n]);
    const float Dv = Dp[d];

    float h[NSTATE];
    #pragma unroll
    for (int n = 0; n < NSTATE; ++n) h[n] = 0.f;

    for (int l = 0; l < SEQ; ++l) {
        const size_t row = (size_t)b * SEQ + l;
        const float dl = delta[row * D_INNER + d];
        const float uu = u[row * D_INNER + d];
        const float* p = xdbl + row * 96 + DT_RANK;
        float4 B0 = *(const float4*)(p + 0);
        float4 B1 = *(const float4*)(p + 4);
        float4 B2 = *(const float4*)(p + 8);
        float4 B3 = *(const float4*)(p + 12);
        float4 C0 = *(const float4*)(p + 16);
        float4 C1 = *(const float4*)(p + 20);
        float4 C2 = *(const float4*)(p + 24);
        float4 C3 = *(const float4*)(p + 28);
        const float Bv[NSTATE] = {B0.x, B0.y, B0.z, B0.w, B1.x, B1.y, B1.z, B1.w,
                                  B2.x, B2.y, B2.z, B2.w, B3.x, B3.y, B3.z, B3.w};
        const float Cv[NSTATE] = {C0.x, C0.y, C0.z, C0.w, C1.x, C1.y, C1.z, C1.w,
                                  C2.x, C2.y, C2.z, C2.w, C3.x, C3.y, C3.z, C3.w};
        const float du = dl * uu;
        float y = 0.f;
        #pragma unroll
        for (int n = 0; n < NSTATE; ++n) {
            const float dA = expf(dl * A[n]);
            h[n] = fmaf(dA, h[n], du * Bv[n]);
            y = fmaf(h[n], Cv[n], y);
        }
        const float r = xr[row * (2 * D_INNER) + D_INNER + d];
        const float g = r / (1.f + expf(-r));
        yg[row * D_INNER + d] = (y + uu * Dv) * g;
    }
}

// ---------------------------------------------------------------------------
extern "C" void kernel_launch(void* const* d_in, const int* in_sizes, int n_in,
                              void* d_out, int out_size, void* d_ws, size_t ws_size,
                              hipStream_t stream)
{
    const float* x     = (const float*)d_in[0];   // [4,1024,1024]
    const float* W_in  = (const float*)d_in[1];   // [4096,1024]
    const float* cw    = (const float*)d_in[2];   // [2048,1,4]
    const float* cb    = (const float*)d_in[3];   // [2048]
    const float* W_x   = (const float*)d_in[4];   // [96,2048]
    const float* W_dt  = (const float*)d_in[5];   // [2048,64]
    const float* b_dt  = (const float*)d_in[6];   // [2048]
    const float* A_log = (const float*)d_in[7];   // [2048,16]
    const float* Dp    = (const float*)d_in[8];   // [2048]
    const float* W_out = (const float*)d_in[9];   // [1024,2048]
    float* out = (float*)d_out;                   // [4096,1024]

    // workspace layout (floats)
    float* xr   = (float*)d_ws;                       // [NTOK, 4096]  64 MB
    float* xs   = xr + (size_t)NTOK * 2 * D_INNER;    // [NTOK, 2048]  32 MB
    float* xdbl = xs + (size_t)NTOK * D_INNER;        // [NTOK, 96]    1.5 MB
    float* dl   = xdbl + (size_t)NTOK * 96;           // [NTOK, 2048]  32 MB (delta, then yg)

    // 1) in_proj: xr = x @ W_in^T   [4096,4096]
    gemm_nt<<<dim3(2 * D_INNER / 128, NTOK / 128), 256, 0, stream>>>(
        x, W_in, xr, NTOK, 2 * D_INNER, D_MODEL, D_MODEL, D_MODEL, 2 * D_INNER);

    // 2) causal conv + SiLU -> xs
    conv_silu<<<dim3(NTOK * D_INNER / 256), 256, 0, stream>>>(xr, cw, cb, xs);

    // 3) x_proj: xdbl = xs @ W_x^T  [4096,96]
    gemm_nt<<<dim3(1, NTOK / 128), 256, 0, stream>>>(
        xs, W_x, xdbl, NTOK, DT_RANK + 2 * NSTATE, D_INNER, D_INNER, D_INNER, 96);

    // 4) dt_proj: dl = xdbl[:, :64] @ W_dt^T  [4096,2048]
    gemm_nt<<<dim3(D_INNER / 128, NTOK / 128), 256, 0, stream>>>(
        xdbl, W_dt, dl, NTOK, D_INNER, DT_RANK, 96, DT_RANK, D_INNER);

    // 5) delta = softplus(dl + b_dt), in place
    bias_softplus<<<dim3(NTOK * D_INNER / 256), 256, 0, stream>>>(dl, b_dt);

    // 6) selective scan + skip + gate -> yg (in place of dl)
    scan_silu_gate<<<dim3(BATCH * D_INNER / 64), 64, 0, stream>>>(
        xs, dl, xdbl, A_log, Dp, xr, dl);

    // 7) out_proj: out = yg @ W_out^T  [4096,1024]
    gemm_nt<<<dim3(D_MODEL / 128, NTOK / 128), 256, 0, stream>>>(
        dl, W_out, out, NTOK, D_MODEL, D_INNER, D_INNER, D_INNER, D_MODEL);
}

// Round 2
// 2369.375 us; speedup vs baseline: 1.1100x; 1.1100x over previous
//
#include <hip/hip_runtime.h>
#include <math.h>

#define D_MODEL 1024
#define D_INNER 2048
#define DT_RANK 64
#define NSTATE  16
#define BATCH   4
#define SEQ     1024
#define NTOK    (BATCH * SEQ)   // 4096 tokens

// ---------------------------------------------------------------------------
// Generic fp32 GEMM:  C[M,N] = A[M,K] * W[N,K]^T
// 128x128 tile, BK=16, 256 threads, 8x8 micro-tile per thread.
// M assumed multiple of 128, K multiple of 16; N guarded (for N=96 case).
// ---------------------------------------------------------------------------
__global__ __launch_bounds__(256) void gemm_nt(
    const float* __restrict__ A, const float* __restrict__ W, float* __restrict__ C,
    int M, int N, int K, int lda, int ldw, int ldc)
{
    __shared__ float As[128][17];
    __shared__ float Ws[128][17];

    const int tid = threadIdx.x;
    const int m0 = blockIdx.y * 128;
    const int n0 = blockIdx.x * 128;
    const int tx = tid & 15;        // 0..15 -> n
    const int ty = tid >> 4;        // 0..15 -> m
    const int lr = tid >> 1;        // 0..127 loader row
    const int lk = (tid & 1) * 8;   // 0 or 8 loader k offset

    float c[8][8];
    #pragma unroll
    for (int i = 0; i < 8; ++i)
        #pragma unroll
        for (int j = 0; j < 8; ++j) c[i][j] = 0.f;

    const float* Arow = A + (size_t)(m0 + lr) * lda + lk;
    const float* Wrow = W + (size_t)(n0 + lr) * ldw + lk;
    const bool wok = (n0 + lr) < N;

    for (int k0 = 0; k0 < K; k0 += 16) {
        float4 a0 = *(const float4*)(Arow + k0);
        float4 a1 = *(const float4*)(Arow + k0 + 4);
        float4 w0, w1;
        if (wok) {
            w0 = *(const float4*)(Wrow + k0);
            w1 = *(const float4*)(Wrow + k0 + 4);
        } else {
            w0 = make_float4(0.f, 0.f, 0.f, 0.f);
            w1 = make_float4(0.f, 0.f, 0.f, 0.f);
        }
        __syncthreads();   // previous compute done before overwriting LDS
        As[lr][lk + 0] = a0.x; As[lr][lk + 1] = a0.y; As[lr][lk + 2] = a0.z; As[lr][lk + 3] = a0.w;
        As[lr][lk + 4] = a1.x; As[lr][lk + 5] = a1.y; As[lr][lk + 6] = a1.z; As[lr][lk + 7] = a1.w;
        Ws[lr][lk + 0] = w0.x; Ws[lr][lk + 1] = w0.y; Ws[lr][lk + 2] = w0.z; Ws[lr][lk + 3] = w0.w;
        Ws[lr][lk + 4] = w1.x; Ws[lr][lk + 5] = w1.y; Ws[lr][lk + 6] = w1.z; Ws[lr][lk + 7] = w1.w;
        __syncthreads();

        #pragma unroll
        for (int kk = 0; kk < 16; ++kk) {
            float a[8], b[8];
            #pragma unroll
            for (int i = 0; i < 8; ++i) a[i] = As[ty * 8 + i][kk];
            #pragma unroll
            for (int j = 0; j < 8; ++j) b[j] = Ws[tx * 8 + j][kk];
            #pragma unroll
            for (int i = 0; i < 8; ++i)
                #pragma unroll
                for (int j = 0; j < 8; ++j)
                    c[i][j] = fmaf(a[i], b[j], c[i][j]);
        }
    }

    #pragma unroll
    for (int i = 0; i < 8; ++i) {
        const int m = m0 + ty * 8 + i;
        const int nb = n0 + tx * 8;
        float4 v0 = make_float4(c[i][0], c[i][1], c[i][2], c[i][3]);
        float4 v1 = make_float4(c[i][4], c[i][5], c[i][6], c[i][7]);
        if (nb + 4 <= N) *(float4*)(C + (size_t)m * ldc + nb) = v0;
        if (nb + 8 <= N) *(float4*)(C + (size_t)m * ldc + nb + 4) = v1;
    }
}

// ---------------------------------------------------------------------------
// Causal depthwise conv (width 4) + SiLU.  xr: [NTOK, 2*D_INNER], take cols
// [0, D_INNER).  Output xs: [NTOK, D_INNER].
// ---------------------------------------------------------------------------
__global__ __launch_bounds__(256) void conv_silu(
    const float* __restrict__ xr, const float* __restrict__ cw,
    const float* __restrict__ cb, float* __restrict__ xs)
{
    const int idx = blockIdx.x * 256 + threadIdx.x;   // over NTOK*D_INNER
    const int d = idx & (D_INNER - 1);
    const int t = idx >> 11;          // token = b*SEQ + l
    const int l = t & (SEQ - 1);

    float acc = cb[d];
    const float* col = xr + (size_t)t * (2 * D_INNER) + d;
    const float w0 = cw[d * 4 + 0], w1 = cw[d * 4 + 1], w2 = cw[d * 4 + 2], w3 = cw[d * 4 + 3];

    if (l >= 3) {
        acc = fmaf(w0, col[-3 * 2 * D_INNER], acc);
        acc = fmaf(w1, col[-2 * 2 * D_INNER], acc);
        acc = fmaf(w2, col[-1 * 2 * D_INNER], acc);
        acc = fmaf(w3, col[0], acc);
    } else {
        if (l >= 2) acc = fmaf(w1, col[-2 * 2 * D_INNER], acc);
        if (l >= 1) acc = fmaf(w2, col[-1 * 2 * D_INNER], acc);
        acc = fmaf(w3, col[0], acc);
    }
    xs[idx] = acc / (1.f + expf(-acc));   // SiLU
}

// ---------------------------------------------------------------------------
// delta = softplus(dt_lin + b_dt), in place.  [NTOK, D_INNER]
// ---------------------------------------------------------------------------
__global__ __launch_bounds__(256) void bias_softplus(
    float* __restrict__ v, const float* __restrict__ bias)
{
    const int idx = blockIdx.x * 256 + threadIdx.x;
    const int d = idx & (D_INNER - 1);
    float x = v[idx] + bias[d];
    v[idx] = (x > 20.f) ? x : log1pf(expf(x));
}

// ---------------------------------------------------------------------------
// Selective scan + skip (u*Dp) + SiLU(res) gate.
// One LANE per (b,d,n) state triple: 16 lanes per channel, shuffle-reduce y.
// 131072 threads = 2048 waves = 8 waves/CU (vs 1 wave/2CU before).
// Writes yg in place of delta (delta/yg alias; read-before-write within wave).
// ---------------------------------------------------------------------------
__global__ __launch_bounds__(256) void scan_silu_gate(
    const float* __restrict__ u,       // xs   [NTOK, D_INNER]
    const float* delta,                // delta [NTOK, D_INNER] (aliases yg)
    const float* __restrict__ xdbl,    // [NTOK, 96]; B at col 64, C at col 80
    const float* __restrict__ A_log,   // [D_INNER, 16]
    const float* __restrict__ Dp,      // [D_INNER]
    const float* __restrict__ xr,      // res at col D_INNER+d, ld 2*D_INNER
    float* yg)                         // [NTOK, D_INNER] (aliases delta)
{
    const int idx = blockIdx.x * 256 + threadIdx.x;  // 0 .. B*D_INNER*16-1
    const int n  = idx & (NSTATE - 1);
    const int ch = idx >> 4;                         // channel = b*D_INNER + d
    const int d  = ch & (D_INNER - 1);
    const int b  = ch >> 11;

    const float An = -__expf(A_log[d * NSTATE + n]);
    const float Dv = Dp[d];

    float h = 0.f;
    const float* drow = delta + d;
    const float* urow = u + d;
    const float* rrow = xr + D_INNER + d;
    const float* brow = xdbl + DT_RANK + n;
    float* yrow = yg + d;

    for (int l = 0; l < SEQ; ++l) {
        const size_t row = (size_t)b * SEQ + l;
        const float dl = drow[row * D_INNER];
        const float uu = urow[row * D_INNER];
        const float Bv = brow[row * 96];
        const float Cv = brow[row * 96 + NSTATE];
        const float dA = __expf(dl * An);
        h = fmaf(dA, h, dl * uu * Bv);
        float y = h * Cv;
        // reduce across the 16-lane state group
        y += __shfl_xor(y, 1);
        y += __shfl_xor(y, 2);
        y += __shfl_xor(y, 4);
        y += __shfl_xor(y, 8);
        if (n == 0) {
            const float r = rrow[row * (2 * D_INNER)];
            const float g = r / (1.f + __expf(-r));
            yrow[row * D_INNER] = (y + uu * Dv) * g;
        }
    }
}

// ---------------------------------------------------------------------------
extern "C" void kernel_launch(void* const* d_in, const int* in_sizes, int n_in,
                              void* d_out, int out_size, void* d_ws, size_t ws_size,
                              hipStream_t stream)
{
    const float* x     = (const float*)d_in[0];   // [4,1024,1024]
    const float* W_in  = (const float*)d_in[1];   // [4096,1024]
    const float* cw    = (const float*)d_in[2];   // [2048,1,4]
    const float* cb    = (const float*)d_in[3];   // [2048]
    const float* W_x   = (const float*)d_in[4];   // [96,2048]
    const float* W_dt  = (const float*)d_in[5];   // [2048,64]
    const float* b_dt  = (const float*)d_in[6];   // [2048]
    const float* A_log = (const float*)d_in[7];   // [2048,16]
    const float* Dp    = (const float*)d_in[8];   // [2048]
    const float* W_out = (const float*)d_in[9];   // [1024,2048]
    float* out = (float*)d_out;                   // [4096,1024]

    // workspace layout (floats)
    float* xr   = (float*)d_ws;                       // [NTOK, 4096]  64 MB
    float* xs   = xr + (size_t)NTOK * 2 * D_INNER;    // [NTOK, 2048]  32 MB
    float* xdbl = xs + (size_t)NTOK * D_INNER;        // [NTOK, 96]    1.5 MB
    float* dl   = xdbl + (size_t)NTOK * 96;           // [NTOK, 2048]  32 MB (delta, then yg)

    // 1) in_proj: xr = x @ W_in^T   [4096,4096]
    gemm_nt<<<dim3(2 * D_INNER / 128, NTOK / 128), 256, 0, stream>>>(
        x, W_in, xr, NTOK, 2 * D_INNER, D_MODEL, D_MODEL, D_MODEL, 2 * D_INNER);

    // 2) causal conv + SiLU -> xs
    conv_silu<<<dim3(NTOK * D_INNER / 256), 256, 0, stream>>>(xr, cw, cb, xs);

    // 3) x_proj: xdbl = xs @ W_x^T  [4096,96]
    gemm_nt<<<dim3(1, NTOK / 128), 256, 0, stream>>>(
        xs, W_x, xdbl, NTOK, DT_RANK + 2 * NSTATE, D_INNER, D_INNER, D_INNER, 96);

    // 4) dt_proj: dl = xdbl[:, :64] @ W_dt^T  [4096,2048]
    gemm_nt<<<dim3(D_INNER / 128, NTOK / 128), 256, 0, stream>>>(
        xdbl, W_dt, dl, NTOK, D_INNER, DT_RANK, 96, DT_RANK, D_INNER);

    // 5) delta = softplus(dl + b_dt), in place
    bias_softplus<<<dim3(NTOK * D_INNER / 256), 256, 0, stream>>>(dl, b_dt);

    // 6) selective scan + skip + gate -> yg (in place of dl), lane-per-state
    scan_silu_gate<<<dim3(BATCH * D_INNER * NSTATE / 256), 256, 0, stream>>>(
        xs, dl, xdbl, A_log, Dp, xr, dl);

    // 7) out_proj: out = yg @ W_out^T  [4096,1024]
    gemm_nt<<<dim3(D_MODEL / 128, NTOK / 128), 256, 0, stream>>>(
        dl, W_out, out, NTOK, D_MODEL, D_INNER, D_INNER, D_INNER, D_MODEL);
}

// Round 3
// 1841.861 us; speedup vs baseline: 1.4279x; 1.2864x over previous
//
#include <hip/hip_runtime.h>
#include <math.h>

#define D_MODEL 1024
#define D_INNER 2048
#define DT_RANK 64
#define NSTATE  16
#define BATCH   4
#define SEQ     1024
#define NTOK    (BATCH * SEQ)   // 4096 tokens
#define NCHUNK  8
#define CLEN    (SEQ / NCHUNK)  // 128

// ---------------------------------------------------------------------------
// Generic fp32 GEMM:  C[M,N] = A[M,K] * W[N,K]^T
// 128x128 tile, BK=16, 256 threads, 8x8 micro-tile per thread.
// ---------------------------------------------------------------------------
__global__ __launch_bounds__(256) void gemm_nt(
    const float* __restrict__ A, const float* __restrict__ W, float* __restrict__ C,
    int M, int N, int K, int lda, int ldw, int ldc)
{
    __shared__ float As[128][17];
    __shared__ float Ws[128][17];

    const int tid = threadIdx.x;
    const int m0 = blockIdx.y * 128;
    const int n0 = blockIdx.x * 128;
    const int tx = tid & 15;
    const int ty = tid >> 4;
    const int lr = tid >> 1;
    const int lk = (tid & 1) * 8;

    float c[8][8];
    #pragma unroll
    for (int i = 0; i < 8; ++i)
        #pragma unroll
        for (int j = 0; j < 8; ++j) c[i][j] = 0.f;

    const float* Arow = A + (size_t)(m0 + lr) * lda + lk;
    const float* Wrow = W + (size_t)(n0 + lr) * ldw + lk;
    const bool wok = (n0 + lr) < N;

    for (int k0 = 0; k0 < K; k0 += 16) {
        float4 a0 = *(const float4*)(Arow + k0);
        float4 a1 = *(const float4*)(Arow + k0 + 4);
        float4 w0, w1;
        if (wok) {
            w0 = *(const float4*)(Wrow + k0);
            w1 = *(const float4*)(Wrow + k0 + 4);
        } else {
            w0 = make_float4(0.f, 0.f, 0.f, 0.f);
            w1 = make_float4(0.f, 0.f, 0.f, 0.f);
        }
        __syncthreads();
        As[lr][lk + 0] = a0.x; As[lr][lk + 1] = a0.y; As[lr][lk + 2] = a0.z; As[lr][lk + 3] = a0.w;
        As[lr][lk + 4] = a1.x; As[lr][lk + 5] = a1.y; As[lr][lk + 6] = a1.z; As[lr][lk + 7] = a1.w;
        Ws[lr][lk + 0] = w0.x; Ws[lr][lk + 1] = w0.y; Ws[lr][lk + 2] = w0.z; Ws[lr][lk + 3] = w0.w;
        Ws[lr][lk + 4] = w1.x; Ws[lr][lk + 5] = w1.y; Ws[lr][lk + 6] = w1.z; Ws[lr][lk + 7] = w1.w;
        __syncthreads();

        #pragma unroll
        for (int kk = 0; kk < 16; ++kk) {
            float a[8], b[8];
            #pragma unroll
            for (int i = 0; i < 8; ++i) a[i] = As[ty * 8 + i][kk];
            #pragma unroll
            for (int j = 0; j < 8; ++j) b[j] = Ws[tx * 8 + j][kk];
            #pragma unroll
            for (int i = 0; i < 8; ++i)
                #pragma unroll
                for (int j = 0; j < 8; ++j)
                    c[i][j] = fmaf(a[i], b[j], c[i][j]);
        }
    }

    #pragma unroll
    for (int i = 0; i < 8; ++i) {
        const int m = m0 + ty * 8 + i;
        const int nb = n0 + tx * 8;
        float4 v0 = make_float4(c[i][0], c[i][1], c[i][2], c[i][3]);
        float4 v1 = make_float4(c[i][4], c[i][5], c[i][6], c[i][7]);
        if (nb + 4 <= N) *(float4*)(C + (size_t)m * ldc + nb) = v0;
        if (nb + 8 <= N) *(float4*)(C + (size_t)m * ldc + nb + 4) = v1;
    }
}

// ---------------------------------------------------------------------------
// Causal depthwise conv (width 4) + SiLU.
// ---------------------------------------------------------------------------
__global__ __launch_bounds__(256) void conv_silu(
    const float* __restrict__ xr, const float* __restrict__ cw,
    const float* __restrict__ cb, float* __restrict__ xs)
{
    const int idx = blockIdx.x * 256 + threadIdx.x;
    const int d = idx & (D_INNER - 1);
    const int t = idx >> 11;
    const int l = t & (SEQ - 1);

    float acc = cb[d];
    const float* col = xr + (size_t)t * (2 * D_INNER) + d;
    const float w0 = cw[d * 4 + 0], w1 = cw[d * 4 + 1], w2 = cw[d * 4 + 2], w3 = cw[d * 4 + 3];

    if (l >= 3) {
        acc = fmaf(w0, col[-3 * 2 * D_INNER], acc);
        acc = fmaf(w1, col[-2 * 2 * D_INNER], acc);
        acc = fmaf(w2, col[-1 * 2 * D_INNER], acc);
        acc = fmaf(w3, col[0], acc);
    } else {
        if (l >= 2) acc = fmaf(w1, col[-2 * 2 * D_INNER], acc);
        if (l >= 1) acc = fmaf(w2, col[-1 * 2 * D_INNER], acc);
        acc = fmaf(w3, col[0], acc);
    }
    xs[idx] = acc / (1.f + expf(-acc));
}

// ---------------------------------------------------------------------------
// delta = softplus(dt_lin + b_dt), in place.
// ---------------------------------------------------------------------------
__global__ __launch_bounds__(256) void bias_softplus(
    float* __restrict__ v, const float* __restrict__ bias)
{
    const int idx = blockIdx.x * 256 + threadIdx.x;
    const int d = idx & (D_INNER - 1);
    float x = v[idx] + bias[d];
    v[idx] = (x > 20.f) ? x : log1pf(expf(x));
}

// ---------------------------------------------------------------------------
// Chunked selective scan.
// Lane mapping (pass1/pass2): idx = ((b*NCHUNK + c)*D_INNER + d)*16 + n
//   -> wave = 4 consecutive d of one (b,c); 16 n-lanes broadcast delta/u,
//      read B/C contiguously.
// ---------------------------------------------------------------------------
__global__ __launch_bounds__(256) void scan_pass1(
    const float* __restrict__ u,       // xs [NTOK, D_INNER]
    const float* __restrict__ delta,   // [NTOK, D_INNER]
    const float* __restrict__ xdbl,    // [NTOK, 96]
    const float* __restrict__ A_log,   // [D_INNER, 16]
    float* __restrict__ P,             // [B, NCHUNK, D_INNER, 16]
    float* __restrict__ hloc)          // same shape
{
    const int idx = blockIdx.x * 256 + threadIdx.x;
    const int n  = idx & (NSTATE - 1);
    const int t  = idx >> 4;
    const int d  = t & (D_INNER - 1);
    const int t2 = t >> 11;
    const int c  = t2 & (NCHUNK - 1);
    const int b  = t2 >> 3;

    const float An = -__expf(A_log[d * NSTATE + n]);
    float p = 1.f, h = 0.f;
    const int l0 = c * CLEN;

    for (int j = 0; j < CLEN; ++j) {
        const size_t row = (size_t)b * SEQ + l0 + j;
        const float dl = delta[row * D_INNER + d];
        const float uu = u[row * D_INNER + d];
        const float Bv = xdbl[row * 96 + DT_RANK + n];
        const float dA = __expf(dl * An);
        p *= dA;
        h = fmaf(dA, h, dl * uu * Bv);
    }
    P[idx] = p;
    hloc[idx] = h;
}

// one thread per (b,d,n): propagate h across the 8 chunks
__global__ __launch_bounds__(256) void scan_carry(
    const float* __restrict__ P, const float* __restrict__ hloc,
    float* __restrict__ hin)
{
    const int idx = blockIdx.x * 256 + threadIdx.x;   // B*D_INNER*16
    const int n = idx & (NSTATE - 1);
    const int d = (idx >> 4) & (D_INNER - 1);
    const int b = idx >> 15;
    const size_t base = ((size_t)b * NCHUNK * D_INNER + d) * 16 + n;
    const size_t cs = (size_t)D_INNER * 16;
    float h = 0.f;
    #pragma unroll
    for (int c = 0; c < NCHUNK; ++c) {
        const size_t a = base + c * cs;
        hin[a] = h;
        h = fmaf(P[a], h, hloc[a]);
    }
}

__global__ __launch_bounds__(256) void scan_pass2(
    const float* __restrict__ u,
    const float* delta,                // aliases yg
    const float* __restrict__ xdbl,
    const float* __restrict__ A_log,
    const float* __restrict__ Dp,
    const float* __restrict__ xr,      // res at col D_INNER+d, ld 2*D_INNER
    const float* __restrict__ hin,
    float* yg)
{
    const int idx = blockIdx.x * 256 + threadIdx.x;
    const int n  = idx & (NSTATE - 1);
    const int t  = idx >> 4;
    const int d  = t & (D_INNER - 1);
    const int t2 = t >> 11;
    const int c  = t2 & (NCHUNK - 1);
    const int b  = t2 >> 3;

    const float An = -__expf(A_log[d * NSTATE + n]);
    const float Dv = Dp[d];
    float h = hin[idx];
    const int l0 = c * CLEN;

    for (int j = 0; j < CLEN; ++j) {
        const size_t row = (size_t)b * SEQ + l0 + j;
        const float dl = delta[row * D_INNER + d];
        const float uu = u[row * D_INNER + d];
        const float Bv = xdbl[row * 96 + DT_RANK + n];
        const float Cv = xdbl[row * 96 + DT_RANK + NSTATE + n];
        const float dA = __expf(dl * An);
        h = fmaf(dA, h, dl * uu * Bv);
        float y = h * Cv;
        y += __shfl_xor(y, 1);
        y += __shfl_xor(y, 2);
        y += __shfl_xor(y, 4);
        y += __shfl_xor(y, 8);
        if (n == 0) {
            const float r = xr[row * (2 * D_INNER) + D_INNER + d];
            const float g = r / (1.f + __expf(-r));
            yg[row * D_INNER + d] = (y + uu * Dv) * g;
        }
    }
}

// ---------------------------------------------------------------------------
extern "C" void kernel_launch(void* const* d_in, const int* in_sizes, int n_in,
                              void* d_out, int out_size, void* d_ws, size_t ws_size,
                              hipStream_t stream)
{
    const float* x     = (const float*)d_in[0];
    const float* W_in  = (const float*)d_in[1];
    const float* cw    = (const float*)d_in[2];
    const float* cb    = (const float*)d_in[3];
    const float* W_x   = (const float*)d_in[4];
    const float* W_dt  = (const float*)d_in[5];
    const float* b_dt  = (const float*)d_in[6];
    const float* A_log = (const float*)d_in[7];
    const float* Dp    = (const float*)d_in[8];
    const float* W_out = (const float*)d_in[9];
    float* out = (float*)d_out;

    // workspace layout (floats)
    float* xr   = (float*)d_ws;                       // [NTOK, 4096]  64 MB
    float* xs   = xr + (size_t)NTOK * 2 * D_INNER;    // [NTOK, 2048]  32 MB
    float* xdbl = xs + (size_t)NTOK * D_INNER;        // [NTOK, 96]    1.5 MB
    float* dl   = xdbl + (size_t)NTOK * 96;           // [NTOK, 2048]  32 MB (delta, then yg)
    float* Pbuf = dl + (size_t)NTOK * D_INNER;        // [B,NCHUNK,D,16]  4 MB
    float* hloc = Pbuf + (size_t)BATCH * NCHUNK * D_INNER * 16;   // 4 MB
    float* hin  = hloc + (size_t)BATCH * NCHUNK * D_INNER * 16;   // 4 MB

    // 1) in_proj
    gemm_nt<<<dim3(2 * D_INNER / 128, NTOK / 128), 256, 0, stream>>>(
        x, W_in, xr, NTOK, 2 * D_INNER, D_MODEL, D_MODEL, D_MODEL, 2 * D_INNER);

    // 2) conv + SiLU
    conv_silu<<<dim3(NTOK * D_INNER / 256), 256, 0, stream>>>(xr, cw, cb, xs);

    // 3) x_proj
    gemm_nt<<<dim3(1, NTOK / 128), 256, 0, stream>>>(
        xs, W_x, xdbl, NTOK, DT_RANK + 2 * NSTATE, D_INNER, D_INNER, D_INNER, 96);

    // 4) dt_proj
    gemm_nt<<<dim3(D_INNER / 128, NTOK / 128), 256, 0, stream>>>(
        xdbl, W_dt, dl, NTOK, D_INNER, DT_RANK, 96, DT_RANK, D_INNER);

    // 5) softplus
    bias_softplus<<<dim3(NTOK * D_INNER / 256), 256, 0, stream>>>(dl, b_dt);

    // 6) chunked selective scan
    const int scan_threads = BATCH * NCHUNK * D_INNER * NSTATE;   // 1M
    scan_pass1<<<dim3(scan_threads / 256), 256, 0, stream>>>(
        xs, dl, xdbl, A_log, Pbuf, hloc);
    scan_carry<<<dim3(BATCH * D_INNER * NSTATE / 256), 256, 0, stream>>>(
        Pbuf, hloc, hin);
    scan_pass2<<<dim3(scan_threads / 256), 256, 0, stream>>>(
        xs, dl, xdbl, A_log, Dp, xr, hin, dl);

    // 7) out_proj
    gemm_nt<<<dim3(D_MODEL / 128, NTOK / 128), 256, 0, stream>>>(
        dl, W_out, out, NTOK, D_MODEL, D_INNER, D_INNER, D_INNER, D_MODEL);
}

// Round 4
// 603.288 us; speedup vs baseline: 4.3596x; 3.0530x over previous
//
#include <hip/hip_runtime.h>
#include <math.h>

#define D_MODEL 1024
#define D_INNER 2048
#define DT_RANK 64
#define NSTATE  16
#define BATCH   4
#define SEQ     1024
#define NTOK    (BATCH * SEQ)   // 4096 tokens
#define NCHUNK  8
#define CLEN    (SEQ / NCHUNK)  // 128

typedef __attribute__((ext_vector_type(8))) short bf16x8;
typedef __attribute__((ext_vector_type(4))) float f32x4;

// ---------------------------------------------------------------------------
// fp32 -> bf16 (round-to-nearest-even), 8 elems/thread
// ---------------------------------------------------------------------------
__device__ __forceinline__ ushort f2bf(float f) {
    unsigned int u = __float_as_uint(f);
    u += 0x7fffu + ((u >> 16) & 1u);
    return (ushort)(u >> 16);
}

__global__ __launch_bounds__(256) void cvt_bf16(
    const float* __restrict__ in, ushort* __restrict__ out, int n8)
{
    const int i = blockIdx.x * 256 + threadIdx.x;
    if (i >= n8) return;
    const float4 a = ((const float4*)in)[2 * i];
    const float4 b = ((const float4*)in)[2 * i + 1];
    ushort4 r0, r1;
    r0.x = f2bf(a.x); r0.y = f2bf(a.y); r0.z = f2bf(a.z); r0.w = f2bf(a.w);
    r1.x = f2bf(b.x); r1.y = f2bf(b.y); r1.z = f2bf(b.z); r1.w = f2bf(b.w);
    ((ushort4*)out)[2 * i]     = r0;
    ((ushort4*)out)[2 * i + 1] = r1;
}

// ---------------------------------------------------------------------------
// bf16 MFMA GEMM:  C[M,N](fp32) = A[M,K](bf16) * W[N,K](bf16)^T
// 128x128 block tile, 256 threads = 4 waves (2x2), 64x64 per wave as 4x4
// mfma_f32_16x16x32_bf16 tiles.  BK=32 staged via global_load_lds width=16.
// M multiple of 128; K multiple of 32; store guarded by Nstore (W buffer must
// be readable for ceil(N/128)*128 rows).
// ---------------------------------------------------------------------------
__device__ __forceinline__ void gload16(const ushort* g, ushort* l) {
    __builtin_amdgcn_global_load_lds(
        (const __attribute__((address_space(1))) unsigned int*)g,
        (__attribute__((address_space(3))) unsigned int*)l, 16, 0, 0);
}

__global__ __launch_bounds__(256) void gemm_bf16(
    const ushort* __restrict__ A, const ushort* __restrict__ W, float* __restrict__ C,
    int K, int lda, int ldw, int ldc, int Nstore)
{
    __shared__ __align__(16) ushort As[128 * 32];
    __shared__ __align__(16) ushort Ws[128 * 32];

    const int tid  = threadIdx.x;
    const int m0   = blockIdx.y * 128;
    const int n0   = blockIdx.x * 128;
    const int wv   = tid >> 6;
    const int lane = tid & 63;
    const int lr   = lane & 15;   // row within 16-tile (A) / col (C)
    const int quad = lane >> 4;   // 0..3
    const int wr   = (wv >> 1) * 64;
    const int wc   = (wv & 1) * 64;

    // staging: chunk q (16B) covers LDS elems [q*8, q*8+8); row=q>>2, col=(q&3)*8
    const int q0 = tid, q1 = 256 + tid;
    const ushort* Ag0 = A + (size_t)(m0 + (q0 >> 2)) * lda + (q0 & 3) * 8;
    const ushort* Ag1 = A + (size_t)(m0 + (q1 >> 2)) * lda + (q1 & 3) * 8;
    const ushort* Wg0 = W + (size_t)(n0 + (q0 >> 2)) * ldw + (q0 & 3) * 8;
    const ushort* Wg1 = W + (size_t)(n0 + (q1 >> 2)) * ldw + (q1 & 3) * 8;
    ushort* AsD0 = As + wv * 512;          // wave-uniform LDS bases
    ushort* AsD1 = As + 2048 + wv * 512;
    ushort* WsD0 = Ws + wv * 512;
    ushort* WsD1 = Ws + 2048 + wv * 512;

    f32x4 acc[4][4];
    #pragma unroll
    for (int i = 0; i < 4; ++i)
        #pragma unroll
        for (int j = 0; j < 4; ++j)
            acc[i][j] = (f32x4){0.f, 0.f, 0.f, 0.f};

    for (int k0 = 0; k0 < K; k0 += 32) {
        gload16(Ag0 + k0, AsD0);
        gload16(Ag1 + k0, AsD1);
        gload16(Wg0 + k0, WsD0);
        gload16(Wg1 + k0, WsD1);
        __syncthreads();   // drains vmcnt(0): staging visible to all

        bf16x8 af[4], bw[4];
        #pragma unroll
        for (int i = 0; i < 4; ++i)
            af[i] = *(const bf16x8*)&As[(wr + i * 16 + lr) * 32 + quad * 8];
        #pragma unroll
        for (int j = 0; j < 4; ++j)
            bw[j] = *(const bf16x8*)&Ws[(wc + j * 16 + lr) * 32 + quad * 8];
        #pragma unroll
        for (int i = 0; i < 4; ++i)
            #pragma unroll
            for (int j = 0; j < 4; ++j)
                acc[i][j] = __builtin_amdgcn_mfma_f32_16x16x32_bf16(
                    af[i], bw[j], acc[i][j], 0, 0, 0);
        __syncthreads();   // LDS reads done before next staging
    }

    // C/D layout: col = lane&15, row = quad*4 + reg   [m89/m91 verified]
    #pragma unroll
    for (int i = 0; i < 4; ++i) {
        const int row = m0 + wr + i * 16 + quad * 4;
        #pragma unroll
        for (int j = 0; j < 4; ++j) {
            const int col = n0 + wc + j * 16 + lr;
            if (col < Nstore) {
                #pragma unroll
                for (int r = 0; r < 4; ++r)
                    C[(size_t)(row + r) * ldc + col] = acc[i][j][r];
            }
        }
    }
}

// ---------------------------------------------------------------------------
// Causal depthwise conv (width 4) + SiLU.
// ---------------------------------------------------------------------------
__global__ __launch_bounds__(256) void conv_silu(
    const float* __restrict__ xr, const float* __restrict__ cw,
    const float* __restrict__ cb, float* __restrict__ xs)
{
    const int idx = blockIdx.x * 256 + threadIdx.x;
    const int d = idx & (D_INNER - 1);
    const int t = idx >> 11;
    const int l = t & (SEQ - 1);

    float acc = cb[d];
    const float* col = xr + (size_t)t * (2 * D_INNER) + d;
    const float w0 = cw[d * 4 + 0], w1 = cw[d * 4 + 1], w2 = cw[d * 4 + 2], w3 = cw[d * 4 + 3];

    if (l >= 3) {
        acc = fmaf(w0, col[-3 * 2 * D_INNER], acc);
        acc = fmaf(w1, col[-2 * 2 * D_INNER], acc);
        acc = fmaf(w2, col[-1 * 2 * D_INNER], acc);
        acc = fmaf(w3, col[0], acc);
    } else {
        if (l >= 2) acc = fmaf(w1, col[-2 * 2 * D_INNER], acc);
        if (l >= 1) acc = fmaf(w2, col[-1 * 2 * D_INNER], acc);
        acc = fmaf(w3, col[0], acc);
    }
    xs[idx] = acc / (1.f + expf(-acc));
}

// ---------------------------------------------------------------------------
// delta = softplus(dt_lin + b_dt), in place.
// ---------------------------------------------------------------------------
__global__ __launch_bounds__(256) void bias_softplus(
    float* __restrict__ v, const float* __restrict__ bias)
{
    const int idx = blockIdx.x * 256 + threadIdx.x;
    const int d = idx & (D_INNER - 1);
    float x = v[idx] + bias[d];
    v[idx] = (x > 20.f) ? x : log1pf(expf(x));
}

// ---------------------------------------------------------------------------
// Chunked selective scan (3 phases), unchanged from R3.
// ---------------------------------------------------------------------------
__global__ __launch_bounds__(256) void scan_pass1(
    const float* __restrict__ u, const float* __restrict__ delta,
    const float* __restrict__ xdbl, const float* __restrict__ A_log,
    float* __restrict__ P, float* __restrict__ hloc)
{
    const int idx = blockIdx.x * 256 + threadIdx.x;
    const int n  = idx & (NSTATE - 1);
    const int t  = idx >> 4;
    const int d  = t & (D_INNER - 1);
    const int t2 = t >> 11;
    const int c  = t2 & (NCHUNK - 1);
    const int b  = t2 >> 3;

    const float An = -__expf(A_log[d * NSTATE + n]);
    float p = 1.f, h = 0.f;
    const int l0 = c * CLEN;

    for (int j = 0; j < CLEN; ++j) {
        const size_t row = (size_t)b * SEQ + l0 + j;
        const float dl = delta[row * D_INNER + d];
        const float uu = u[row * D_INNER + d];
        const float Bv = xdbl[row * 96 + DT_RANK + n];
        const float dA = __expf(dl * An);
        p *= dA;
        h = fmaf(dA, h, dl * uu * Bv);
    }
    P[idx] = p;
    hloc[idx] = h;
}

__global__ __launch_bounds__(256) void scan_carry(
    const float* __restrict__ P, const float* __restrict__ hloc,
    float* __restrict__ hin)
{
    const int idx = blockIdx.x * 256 + threadIdx.x;
    const int n = idx & (NSTATE - 1);
    const int d = (idx >> 4) & (D_INNER - 1);
    const int b = idx >> 15;
    const size_t base = ((size_t)b * NCHUNK * D_INNER + d) * 16 + n;
    const size_t cs = (size_t)D_INNER * 16;
    float h = 0.f;
    #pragma unroll
    for (int c = 0; c < NCHUNK; ++c) {
        const size_t a = base + c * cs;
        hin[a] = h;
        h = fmaf(P[a], h, hloc[a]);
    }
}

__global__ __launch_bounds__(256) void scan_pass2(
    const float* __restrict__ u, const float* delta,
    const float* __restrict__ xdbl, const float* __restrict__ A_log,
    const float* __restrict__ Dp, const float* __restrict__ xr,
    const float* __restrict__ hin, float* yg)
{
    const int idx = blockIdx.x * 256 + threadIdx.x;
    const int n  = idx & (NSTATE - 1);
    const int t  = idx >> 4;
    const int d  = t & (D_INNER - 1);
    const int t2 = t >> 11;
    const int c  = t2 & (NCHUNK - 1);
    const int b  = t2 >> 3;

    const float An = -__expf(A_log[d * NSTATE + n]);
    const float Dv = Dp[d];
    float h = hin[idx];
    const int l0 = c * CLEN;

    for (int j = 0; j < CLEN; ++j) {
        const size_t row = (size_t)b * SEQ + l0 + j;
        const float dl = delta[row * D_INNER + d];
        const float uu = u[row * D_INNER + d];
        const float Bv = xdbl[row * 96 + DT_RANK + n];
        const float Cv = xdbl[row * 96 + DT_RANK + NSTATE + n];
        const float dA = __expf(dl * An);
        h = fmaf(dA, h, dl * uu * Bv);
        float y = h * Cv;
        y += __shfl_xor(y, 1);
        y += __shfl_xor(y, 2);
        y += __shfl_xor(y, 4);
        y += __shfl_xor(y, 8);
        if (n == 0) {
            const float r = xr[row * (2 * D_INNER) + D_INNER + d];
            const float g = r / (1.f + __expf(-r));
            yg[row * D_INNER + d] = (y + uu * Dv) * g;
        }
    }
}

// ---------------------------------------------------------------------------
extern "C" void kernel_launch(void* const* d_in, const int* in_sizes, int n_in,
                              void* d_out, int out_size, void* d_ws, size_t ws_size,
                              hipStream_t stream)
{
    const float* x     = (const float*)d_in[0];
    const float* W_in  = (const float*)d_in[1];
    const float* cw    = (const float*)d_in[2];
    const float* cb    = (const float*)d_in[3];
    const float* W_x   = (const float*)d_in[4];
    const float* W_dt  = (const float*)d_in[5];
    const float* b_dt  = (const float*)d_in[6];
    const float* A_log = (const float*)d_in[7];
    const float* Dp    = (const float*)d_in[8];
    const float* W_out = (const float*)d_in[9];
    float* out = (float*)d_out;

    // ---- workspace layout ----
    float* xr   = (float*)d_ws;                        // [4096,4096] fp32  64 MB
    float* xs   = xr + (size_t)NTOK * 2 * D_INNER;     // [4096,2048] fp32  32 MB
    float* xdbl = xs + (size_t)NTOK * D_INNER;         // [4096,96]   fp32  1.5 MB
    float* dl   = xdbl + (size_t)NTOK * 96;            // [4096,2048] fp32  32 MB
    float* Pbuf = dl + (size_t)NTOK * D_INNER;         // 4 MB
    float* hloc = Pbuf + (size_t)BATCH * NCHUNK * D_INNER * 16;
    float* hin  = hloc + (size_t)BATCH * NCHUNK * D_INNER * 16;
    ushort* bpool  = (ushort*)(hin + (size_t)BATCH * NCHUNK * D_INNER * 16);
    ushort* xb     = bpool;                            // [4096,1024]  8 MB
    ushort* W_in_b = bpool + (size_t)4096 * 1024;      // [4096,1024]  8 MB
    ushort* yg_b   = bpool;                            // alias (xb+W_in_b dead)  16 MB
    ushort* xs_b   = bpool + (size_t)2 * 4096 * 1024;  // [4096,2048] 16 MB
    ushort* W_out_b= xs_b;                             // alias (xs_b dead after x_proj)
    ushort* xdbl_b = xs_b + (size_t)4096 * 2048;       // [4096,96] (pad to 128) 1 MB
    ushort* W_dt_b = xdbl_b + (size_t)512 * 1024;      // [2048,64]  0.25 MB
    ushort* W_x_b  = W_dt_b + (size_t)2048 * 64;       // [128,2048] 0.5 MB (rows 96+ garbage-read OK)

    // 1) in_proj (bf16 MFMA): xr = x @ W_in^T
    cvt_bf16<<<dim3(4096 * 1024 / 8 / 256), 256, 0, stream>>>(x, xb, 4096 * 1024 / 8);
    cvt_bf16<<<dim3(4096 * 1024 / 8 / 256), 256, 0, stream>>>(W_in, W_in_b, 4096 * 1024 / 8);
    gemm_bf16<<<dim3(32, 32), 256, 0, stream>>>(
        xb, W_in_b, xr, D_MODEL, D_MODEL, D_MODEL, 2 * D_INNER, 2 * D_INNER);

    // 2) conv + SiLU
    conv_silu<<<dim3(NTOK * D_INNER / 256), 256, 0, stream>>>(xr, cw, cb, xs);

    // 3) x_proj (bf16 MFMA): xdbl = xs @ W_x^T   (N=96, single col-block)
    cvt_bf16<<<dim3(4096 * 2048 / 8 / 256), 256, 0, stream>>>(xs, xs_b, 4096 * 2048 / 8);
    cvt_bf16<<<dim3(96 * 2048 / 8 / 256), 256, 0, stream>>>(W_x, W_x_b, 96 * 2048 / 8);
    gemm_bf16<<<dim3(1, 32), 256, 0, stream>>>(
        xs_b, W_x_b, xdbl, D_INNER, D_INNER, D_INNER, 96, 96);

    // 4) dt_proj (bf16 MFMA): dl = xdbl[:, :64] @ W_dt^T
    cvt_bf16<<<dim3(NTOK * 96 / 8 / 256), 256, 0, stream>>>(xdbl, xdbl_b, NTOK * 96 / 8);
    cvt_bf16<<<dim3(2048 * 64 / 8 / 256), 256, 0, stream>>>(W_dt, W_dt_b, 2048 * 64 / 8);
    gemm_bf16<<<dim3(16, 32), 256, 0, stream>>>(
        xdbl_b, W_dt_b, dl, DT_RANK, 96, DT_RANK, D_INNER, D_INNER);

    // 5) softplus
    bias_softplus<<<dim3(NTOK * D_INNER / 256), 256, 0, stream>>>(dl, b_dt);

    // 6) chunked selective scan
    const int scan_threads = BATCH * NCHUNK * D_INNER * NSTATE;
    scan_pass1<<<dim3(scan_threads / 256), 256, 0, stream>>>(
        xs, dl, xdbl, A_log, Pbuf, hloc);
    scan_carry<<<dim3(BATCH * D_INNER * NSTATE / 256), 256, 0, stream>>>(
        Pbuf, hloc, hin);
    scan_pass2<<<dim3(scan_threads / 256), 256, 0, stream>>>(
        xs, dl, xdbl, A_log, Dp, xr, hin, dl);

    // 7) out_proj (bf16 MFMA): out = yg @ W_out^T
    cvt_bf16<<<dim3(4096 * 2048 / 8 / 256), 256, 0, stream>>>(dl, yg_b, 4096 * 2048 / 8);
    cvt_bf16<<<dim3(1024 * 2048 / 8 / 256), 256, 0, stream>>>(W_out, W_out_b, 1024 * 2048 / 8);
    gemm_bf16<<<dim3(8, 32), 256, 0, stream>>>(
        yg_b, W_out_b, out, D_INNER, D_INNER, D_INNER, D_MODEL, D_MODEL);
}

// Round 5
// 403.961 us; speedup vs baseline: 6.5107x; 1.4934x over previous
//
#include <hip/hip_runtime.h>
#include <math.h>

#define D_MODEL 1024
#define D_INNER 2048
#define DT_RANK 64
#define NSTATE  16
#define BATCH   4
#define SEQ     1024
#define NTOK    (BATCH * SEQ)   // 4096 tokens
#define NCHUNK  32
#define CLEN    (SEQ / NCHUNK)  // 32

typedef __attribute__((ext_vector_type(8))) short bf16x8;
typedef __attribute__((ext_vector_type(4))) float f32x4;

// ---------------------------------------------------------------------------
// fp32 -> bf16 (round-to-nearest-even)
// ---------------------------------------------------------------------------
__device__ __forceinline__ ushort f2bf(float f) {
    unsigned int u = __float_as_uint(f);
    u += 0x7fffu + ((u >> 16) & 1u);
    return (ushort)(u >> 16);
}

__global__ __launch_bounds__(256) void cvt_bf16(
    const float* __restrict__ in, ushort* __restrict__ out, int n8)
{
    const int i = blockIdx.x * 256 + threadIdx.x;
    if (i >= n8) return;
    const float4 a = ((const float4*)in)[2 * i];
    const float4 b = ((const float4*)in)[2 * i + 1];
    ushort4 r0, r1;
    r0.x = f2bf(a.x); r0.y = f2bf(a.y); r0.z = f2bf(a.z); r0.w = f2bf(a.w);
    r1.x = f2bf(b.x); r1.y = f2bf(b.y); r1.z = f2bf(b.z); r1.w = f2bf(b.w);
    ((ushort4*)out)[2 * i]     = r0;
    ((ushort4*)out)[2 * i + 1] = r1;
}

// ---------------------------------------------------------------------------
// bf16 MFMA GEMM:  C[M,N](fp32) = A[M,K](bf16) * W[N,K](bf16)^T
// 128x128 block tile, 256 threads = 4 waves, 64x64/wave as 4x4 16x16x32 MFMA.
// ---------------------------------------------------------------------------
__device__ __forceinline__ void gload16(const ushort* g, ushort* l) {
    __builtin_amdgcn_global_load_lds(
        (const __attribute__((address_space(1))) unsigned int*)g,
        (__attribute__((address_space(3))) unsigned int*)l, 16, 0, 0);
}

__global__ __launch_bounds__(256) void gemm_bf16(
    const ushort* __restrict__ A, const ushort* __restrict__ W, float* __restrict__ C,
    int K, int lda, int ldw, int ldc, int Nstore)
{
    __shared__ __align__(16) ushort As[128 * 32];
    __shared__ __align__(16) ushort Ws[128 * 32];

    const int tid  = threadIdx.x;
    const int m0   = blockIdx.y * 128;
    const int n0   = blockIdx.x * 128;
    const int wv   = tid >> 6;
    const int lane = tid & 63;
    const int lr   = lane & 15;
    const int quad = lane >> 4;
    const int wr   = (wv >> 1) * 64;
    const int wc   = (wv & 1) * 64;

    const int q0 = tid, q1 = 256 + tid;
    const ushort* Ag0 = A + (size_t)(m0 + (q0 >> 2)) * lda + (q0 & 3) * 8;
    const ushort* Ag1 = A + (size_t)(m0 + (q1 >> 2)) * lda + (q1 & 3) * 8;
    const ushort* Wg0 = W + (size_t)(n0 + (q0 >> 2)) * ldw + (q0 & 3) * 8;
    const ushort* Wg1 = W + (size_t)(n0 + (q1 >> 2)) * ldw + (q1 & 3) * 8;
    ushort* AsD0 = As + wv * 512;
    ushort* AsD1 = As + 2048 + wv * 512;
    ushort* WsD0 = Ws + wv * 512;
    ushort* WsD1 = Ws + 2048 + wv * 512;

    f32x4 acc[4][4];
    #pragma unroll
    for (int i = 0; i < 4; ++i)
        #pragma unroll
        for (int j = 0; j < 4; ++j)
            acc[i][j] = (f32x4){0.f, 0.f, 0.f, 0.f};

    for (int k0 = 0; k0 < K; k0 += 32) {
        gload16(Ag0 + k0, AsD0);
        gload16(Ag1 + k0, AsD1);
        gload16(Wg0 + k0, WsD0);
        gload16(Wg1 + k0, WsD1);
        __syncthreads();

        bf16x8 af[4], bw[4];
        #pragma unroll
        for (int i = 0; i < 4; ++i)
            af[i] = *(const bf16x8*)&As[(wr + i * 16 + lr) * 32 + quad * 8];
        #pragma unroll
        for (int j = 0; j < 4; ++j)
            bw[j] = *(const bf16x8*)&Ws[(wc + j * 16 + lr) * 32 + quad * 8];
        #pragma unroll
        for (int i = 0; i < 4; ++i)
            #pragma unroll
            for (int j = 0; j < 4; ++j)
                acc[i][j] = __builtin_amdgcn_mfma_f32_16x16x32_bf16(
                    af[i], bw[j], acc[i][j], 0, 0, 0);
        __syncthreads();
    }

    #pragma unroll
    for (int i = 0; i < 4; ++i) {
        const int row = m0 + wr + i * 16 + quad * 4;
        #pragma unroll
        for (int j = 0; j < 4; ++j) {
            const int col = n0 + wc + j * 16 + lr;
            if (col < Nstore) {
                #pragma unroll
                for (int r = 0; r < 4; ++r)
                    C[(size_t)(row + r) * ldc + col] = acc[i][j][r];
            }
        }
    }
}

// ---------------------------------------------------------------------------
// Causal depthwise conv (width 4) + SiLU.  Dual output: fp32 (scan) + bf16
// (x_proj GEMM input).
// ---------------------------------------------------------------------------
__global__ __launch_bounds__(256) void conv_silu(
    const float* __restrict__ xr, const float* __restrict__ cw,
    const float* __restrict__ cb, float* __restrict__ xs,
    ushort* __restrict__ xsb)
{
    const int idx = blockIdx.x * 256 + threadIdx.x;
    const int d = idx & (D_INNER - 1);
    const int t = idx >> 11;
    const int l = t & (SEQ - 1);

    float acc = cb[d];
    const float* col = xr + (size_t)t * (2 * D_INNER) + d;
    const float w0 = cw[d * 4 + 0], w1 = cw[d * 4 + 1], w2 = cw[d * 4 + 2], w3 = cw[d * 4 + 3];

    if (l >= 3) {
        acc = fmaf(w0, col[-3 * 2 * D_INNER], acc);
        acc = fmaf(w1, col[-2 * 2 * D_INNER], acc);
        acc = fmaf(w2, col[-1 * 2 * D_INNER], acc);
        acc = fmaf(w3, col[0], acc);
    } else {
        if (l >= 2) acc = fmaf(w1, col[-2 * 2 * D_INNER], acc);
        if (l >= 1) acc = fmaf(w2, col[-1 * 2 * D_INNER], acc);
        acc = fmaf(w3, col[0], acc);
    }
    const float s = acc / (1.f + expf(-acc));
    xs[idx] = s;
    xsb[idx] = f2bf(s);
}

// ---------------------------------------------------------------------------
// Chunked selective scan, lane-per-(b,c,d), h[16] in registers, no shuffles.
// delta = softplus(dl_raw + b_dt) computed inline (identically in both passes).
// P[n] = exp(An * sum(delta)) — exact product-of-exps refactoring.
// ---------------------------------------------------------------------------
__device__ __forceinline__ float softplus_f(float x) {
    return (x > 20.f) ? x : __logf(1.f + __expf(x));
}

__global__ __launch_bounds__(256, 4) void scan_pass1(
    const float* __restrict__ u,       // xs   [NTOK, D_INNER]
    const float* __restrict__ dlr,     // dt_proj raw [NTOK, D_INNER]
    const float* __restrict__ bdt,     // [D_INNER]
    const float* __restrict__ xdbl,    // [NTOK, 96]
    const float* __restrict__ A_log,   // [D_INNER, 16]
    float* __restrict__ P,             // [(b*NCHUNK+c)*D + d][16]
    float* __restrict__ hloc)
{
    const int idx = blockIdx.x * 256 + threadIdx.x;   // B*NCHUNK*D
    const int d = idx & (D_INNER - 1);
    const int g = idx >> 11;            // b*NCHUNK + c  (wave-uniform)
    const int c = g & (NCHUNK - 1);
    const int b = g >> 5;

    float An[NSTATE];
    {
        const float4* Ap = (const float4*)(A_log + (size_t)d * NSTATE);
        #pragma unroll
        for (int q = 0; q < 4; ++q) {
            float4 a = Ap[q];
            An[q * 4 + 0] = -__expf(a.x);
            An[q * 4 + 1] = -__expf(a.y);
            An[q * 4 + 2] = -__expf(a.z);
            An[q * 4 + 3] = -__expf(a.w);
        }
    }
    const float bd = bdt[d];

    float h[NSTATE];
    #pragma unroll
    for (int n = 0; n < NSTATE; ++n) h[n] = 0.f;
    float sdl = 0.f;

    const size_t rbase = (size_t)b * SEQ + c * CLEN;
    for (int j = 0; j < CLEN; ++j) {
        const size_t row = rbase + j;
        const float dl = softplus_f(dlr[row * D_INNER + d] + bd);
        const float uu = u[row * D_INNER + d];
        const float du = dl * uu;
        sdl += dl;
        const float4* Bp = (const float4*)(xdbl + row * 96 + DT_RANK);
        float Bv[NSTATE];
        #pragma unroll
        for (int q = 0; q < 4; ++q) {
            float4 v = Bp[q];
            Bv[q * 4 + 0] = v.x; Bv[q * 4 + 1] = v.y;
            Bv[q * 4 + 2] = v.z; Bv[q * 4 + 3] = v.w;
        }
        #pragma unroll
        for (int n = 0; n < NSTATE; ++n)
            h[n] = fmaf(__expf(dl * An[n]), h[n], du * Bv[n]);
    }

    float* Pd = P + (size_t)idx * NSTATE;
    float* Hd = hloc + (size_t)idx * NSTATE;
    #pragma unroll
    for (int n = 0; n < NSTATE; ++n) {
        Pd[n] = __expf(An[n] * sdl);
        Hd[n] = h[n];
    }
}

// per (b,d,n): propagate across chunks; hloc is overwritten with h_in.
__global__ __launch_bounds__(256) void scan_carry(
    const float* __restrict__ P, float* __restrict__ hloc)
{
    const int idx = blockIdx.x * 256 + threadIdx.x;   // B*D*16
    const int n = idx & (NSTATE - 1);
    const int d = (idx >> 4) & (D_INNER - 1);
    const int b = idx >> 15;
    const size_t base = ((size_t)b * NCHUNK * D_INNER + d) * NSTATE + n;
    const size_t cs = (size_t)D_INNER * NSTATE;
    float h = 0.f;
    #pragma unroll 4
    for (int c = 0; c < NCHUNK; ++c) {
        const size_t a = base + c * cs;
        const float t = hloc[a];
        const float p = P[a];
        hloc[a] = h;
        h = fmaf(p, h, t);
    }
}

__global__ __launch_bounds__(256, 4) void scan_pass2(
    const float* __restrict__ u,
    const float* __restrict__ dlr,
    const float* __restrict__ bdt,
    const float* __restrict__ xdbl,
    const float* __restrict__ A_log,
    const float* __restrict__ Dp,
    const float* __restrict__ xr,      // res at col D_INNER+d, ld 2*D_INNER
    const float* __restrict__ hin,     // carried h (hloc after scan_carry)
    ushort* __restrict__ ygb)          // bf16 out [NTOK, D_INNER]
{
    const int idx = blockIdx.x * 256 + threadIdx.x;
    const int d = idx & (D_INNER - 1);
    const int g = idx >> 11;
    const int c = g & (NCHUNK - 1);
    const int b = g >> 5;

    float An[NSTATE];
    {
        const float4* Ap = (const float4*)(A_log + (size_t)d * NSTATE);
        #pragma unroll
        for (int q = 0; q < 4; ++q) {
            float4 a = Ap[q];
            An[q * 4 + 0] = -__expf(a.x);
            An[q * 4 + 1] = -__expf(a.y);
            An[q * 4 + 2] = -__expf(a.z);
            An[q * 4 + 3] = -__expf(a.w);
        }
    }
    const float bd = bdt[d];
    const float Dv = Dp[d];

    float h[NSTATE];
    {
        const float4* Hp = (const float4*)(hin + (size_t)idx * NSTATE);
        #pragma unroll
        for (int q = 0; q < 4; ++q) {
            float4 v = Hp[q];
            h[q * 4 + 0] = v.x; h[q * 4 + 1] = v.y;
            h[q * 4 + 2] = v.z; h[q * 4 + 3] = v.w;
        }
    }

    const size_t rbase = (size_t)b * SEQ + c * CLEN;
    for (int j = 0; j < CLEN; ++j) {
        const size_t row = rbase + j;
        const float dl = softplus_f(dlr[row * D_INNER + d] + bd);
        const float uu = u[row * D_INNER + d];
        const float du = dl * uu;
        const float4* Bp = (const float4*)(xdbl + row * 96 + DT_RANK);
        float Bv[NSTATE], Cv[NSTATE];
        #pragma unroll
        for (int q = 0; q < 4; ++q) {
            float4 v = Bp[q];
            Bv[q * 4 + 0] = v.x; Bv[q * 4 + 1] = v.y;
            Bv[q * 4 + 2] = v.z; Bv[q * 4 + 3] = v.w;
            float4 w = Bp[q + 4];
            Cv[q * 4 + 0] = w.x; Cv[q * 4 + 1] = w.y;
            Cv[q * 4 + 2] = w.z; Cv[q * 4 + 3] = w.w;
        }
        float y = 0.f;
        #pragma unroll
        for (int n = 0; n < NSTATE; ++n) {
            h[n] = fmaf(__expf(dl * An[n]), h[n], du * Bv[n]);
            y = fmaf(h[n], Cv[n], y);
        }
        const float r = xr[row * (2 * D_INNER) + D_INNER + d];
        const float gt = r / (1.f + __expf(-r));
        ygb[row * D_INNER + d] = f2bf((y + uu * Dv) * gt);
    }
}

// ---------------------------------------------------------------------------
extern "C" void kernel_launch(void* const* d_in, const int* in_sizes, int n_in,
                              void* d_out, int out_size, void* d_ws, size_t ws_size,
                              hipStream_t stream)
{
    const float* x     = (const float*)d_in[0];
    const float* W_in  = (const float*)d_in[1];
    const float* cw    = (const float*)d_in[2];
    const float* cb    = (const float*)d_in[3];
    const float* W_x   = (const float*)d_in[4];
    const float* W_dt  = (const float*)d_in[5];
    const float* b_dt  = (const float*)d_in[6];
    const float* A_log = (const float*)d_in[7];
    const float* Dp    = (const float*)d_in[8];
    const float* W_out = (const float*)d_in[9];
    float* out = (float*)d_out;

    // ---- workspace layout ----
    float* xr   = (float*)d_ws;                        // [4096,4096] fp32  64 MB
    float* xs   = xr + (size_t)NTOK * 2 * D_INNER;     // [4096,2048] fp32  32 MB
    float* xdbl = xs + (size_t)NTOK * D_INNER;         // [4096,96]   fp32  1.5 MB
    float* dl   = xdbl + (size_t)NTOK * 96;            // [4096,2048] fp32  32 MB (raw dt lin)
    float* Pbuf = dl + (size_t)NTOK * D_INNER;         // [B*NCHUNK*D*16]   16 MB
    float* hloc = Pbuf + (size_t)BATCH * NCHUNK * D_INNER * NSTATE;  // 16 MB
    ushort* bpool  = (ushort*)(hloc + (size_t)BATCH * NCHUNK * D_INNER * NSTATE);
    ushort* xb     = bpool;                            // [4096,1024]  8 MB
    ushort* W_in_b = bpool + (size_t)4096 * 1024;      // [4096,1024]  8 MB
    ushort* yg_b   = bpool;                            // alias (xb/W_in_b dead) 16 MB
    ushort* xs_b   = bpool + (size_t)2 * 4096 * 1024;  // [4096,2048] 16 MB
    ushort* W_out_b= xs_b;                             // alias (xs_b dead after x_proj)
    ushort* xdbl_b = xs_b + (size_t)4096 * 2048;       // [4096,96]  0.8 MB
    ushort* W_dt_b = xdbl_b + (size_t)NTOK * 96;       // [2048,64]  0.25 MB
    ushort* W_x_b  = W_dt_b + (size_t)2048 * 64;       // [128,2048] 0.5 MB

    // 1) in_proj (bf16 MFMA): xr = x @ W_in^T
    cvt_bf16<<<dim3(4096 * 1024 / 8 / 256), 256, 0, stream>>>(x, xb, 4096 * 1024 / 8);
    cvt_bf16<<<dim3(4096 * 1024 / 8 / 256), 256, 0, stream>>>(W_in, W_in_b, 4096 * 1024 / 8);
    gemm_bf16<<<dim3(32, 32), 256, 0, stream>>>(
        xb, W_in_b, xr, D_MODEL, D_MODEL, D_MODEL, 2 * D_INNER, 2 * D_INNER);

    // 2) conv + SiLU -> xs (fp32) + xs_b (bf16)
    conv_silu<<<dim3(NTOK * D_INNER / 256), 256, 0, stream>>>(xr, cw, cb, xs, xs_b);

    // 3) x_proj (bf16 MFMA): xdbl = xs @ W_x^T   (N=96)
    cvt_bf16<<<dim3(96 * 2048 / 8 / 256), 256, 0, stream>>>(W_x, W_x_b, 96 * 2048 / 8);
    gemm_bf16<<<dim3(1, 32), 256, 0, stream>>>(
        xs_b, W_x_b, xdbl, D_INNER, D_INNER, D_INNER, 96, 96);

    // 4) dt_proj (bf16 MFMA): dl = xdbl[:, :64] @ W_dt^T  (raw, bias+softplus in scan)
    cvt_bf16<<<dim3(NTOK * 96 / 8 / 256), 256, 0, stream>>>(xdbl, xdbl_b, NTOK * 96 / 8);
    cvt_bf16<<<dim3(2048 * 64 / 8 / 256), 256, 0, stream>>>(W_dt, W_dt_b, 2048 * 64 / 8);
    gemm_bf16<<<dim3(16, 32), 256, 0, stream>>>(
        xdbl_b, W_dt_b, dl, DT_RANK, 96, DT_RANK, D_INNER, D_INNER);

    // 5) chunked selective scan (softplus fused), bf16 gated output
    const int scan_threads = BATCH * NCHUNK * D_INNER;   // 256K
    scan_pass1<<<dim3(scan_threads / 256), 256, 0, stream>>>(
        xs, dl, b_dt, xdbl, A_log, Pbuf, hloc);
    scan_carry<<<dim3(BATCH * D_INNER * NSTATE / 256), 256, 0, stream>>>(
        Pbuf, hloc);
    scan_pass2<<<dim3(scan_threads / 256), 256, 0, stream>>>(
        xs, dl, b_dt, xdbl, A_log, Dp, xr, hloc, yg_b);

    // 6) out_proj (bf16 MFMA): out = yg @ W_out^T
    cvt_bf16<<<dim3(1024 * 2048 / 8 / 256), 256, 0, stream>>>(W_out, W_out_b, 1024 * 2048 / 8);
    gemm_bf16<<<dim3(8, 32), 256, 0, stream>>>(
        yg_b, W_out_b, out, D_INNER, D_INNER, D_INNER, D_MODEL, D_MODEL);
}